// Round 5
// baseline (599.285 us; speedup 1.0000x reference)
//
#include <hip/hip_runtime.h>
#include <hip/hip_bf16.h>
#include <math.h>

#define B_TOTAL 262144
#define NREG 32
#define BITW 64
#define NSLICE 16
#define SLICE_STRIDE (NREG*128 + NREG)   // 4128 floats per slice (HGS + cnt)

typedef float  f32x16 __attribute__((ext_vector_type(16)));
typedef short  short8 __attribute__((ext_vector_type(8)));
typedef int    i32x4  __attribute__((ext_vector_type(4)));

union FR { i32x4 w; short8 h; };

// v_cvt_pk_bf16_f32: dst.lo16 = bf16(a), dst.hi16 = bf16(b)  (RNE)
__device__ __forceinline__ unsigned pk_bf16(float a, float b){
    unsigned r;
    asm("v_cvt_pk_bf16_f32 %0, %1, %2" : "=v"(r) : "v"(a), "v"(b));
    return r;
}

// exact-erf gelu (used on the tiny att path only)
__device__ __forceinline__ float geluf(float x){
    return 0.5f * x * (1.0f + erff(x * 0.70710678118654752440f));
}

// tanh-form gelu: |err| < ~1.5e-3 abs, damped to ~1e-5 in outputs
__device__ __forceinline__ float gelu_fast(float x){
    float x2 = x*x;
    float t1 = fmaf(x2, 0.044715f, 1.0f);
    float z2 = x * t1 * 1.5957691216057308f;     // 2*sqrt(2/pi)
    float e  = __expf(z2);
    float r  = __builtin_amdgcn_rcpf(e + 1.0f);
    return x - x*r;                               // 0.5x(1+tanh z)
}

// ---------------------------------------------------------------------------
// Fused kernel: blocks 0..31 = attention table; blocks 32..543 = enc/HGS MFMA.
// ---------------------------------------------------------------------------
__global__ void __launch_bounds__(256, 2) k_fused(
    const float* __restrict__ wval, const int* __restrict__ widx,
    const float* __restrict__ vw1, const float* __restrict__ vb1,
    const float* __restrict__ vg1, const float* __restrict__ vbt1,
    const float* __restrict__ qw1, const float* __restrict__ qb1,
    const float* __restrict__ qg1, const float* __restrict__ qbt1,
    const float* __restrict__ qw2, const float* __restrict__ qb2,
    const float* __restrict__ qg2, const float* __restrict__ qbt2,
    const float* __restrict__ qw3, const float* __restrict__ qb3,
    const float* __restrict__ keys, const float* __restrict__ temp_p,
    float* __restrict__ att_out, float* __restrict__ hgs_g)
{
    __shared__ __align__(16) unsigned s_w1p[16*64*4];  // 16 frags x 64 lanes x 4 words
    __shared__ float s_hgs[NREG*128];
    __shared__ float s_cnt[NREG];
    __shared__ float red8[4];
    __shared__ float h1s[128];
    __shared__ float h2s[256];
    __shared__ float qns[256];
    __shared__ float svs[32];

    const int t    = threadIdx.x;
    const int lane = t & 63;
    const int wid  = t >> 6;
    const int l31  = lane & 31;
    const int lh   = lane >> 5;

    if (blockIdx.x < 32){
        // ---------------- attention table path (unchanged, verified) -------
        const int idx = blockIdx.x;
        auto blksum = [&](float v)->float{
            #pragma unroll
            for (int o = 32; o >= 1; o >>= 1) v += __shfl_xor(v, o, 64);
            if (lane == 0) red8[wid] = v;
            __syncthreads();
            float r = red8[0] + red8[1] + red8[2] + red8[3];
            __syncthreads();
            return r;
        };

        float a1 = 0.f;
        if (t < 128){
            a1 = qb1[t];
            #pragma unroll
            for (int k = 0; k < 5; ++k)
                a1 += (float)((idx >> k) & 1) * qw1[k*128 + t];
        }
        float m1 = blksum(t < 128 ? a1 : 0.f) * (1.f/128.f);
        float d1 = (t < 128) ? (a1 - m1) : 0.f;
        float v1 = blksum(d1*d1) * (1.f/128.f);
        if (t < 128) h1s[t] = geluf(d1 * rsqrtf(v1 + 1e-5f) * qg1[t] + qbt1[t]);
        __syncthreads();

        float a2 = qb2[t];
        for (int k = 0; k < 128; ++k) a2 += h1s[k] * qw2[k*256 + t];
        float m2 = blksum(a2) * (1.f/256.f);
        float d2 = a2 - m2;
        float v2 = blksum(d2*d2) * (1.f/256.f);
        h2s[t] = geluf(d2 * rsqrtf(v2 + 1e-5f) * qg2[t] + qbt2[t]);
        __syncthreads();

        float a3 = qb3[t];
        for (int k = 0; k < 256; ++k) a3 += h2s[k] * qw3[k*256 + t];
        float nrm = blksum(a3*a3);
        qns[t] = a3 / fmaxf(sqrtf(nrm), 1e-12f);
        __syncthreads();

        if (t < 32){
            const float* kr = keys + t * 256;
            float dot = 0.f, ss = 0.f;
            for (int k = 0; k < 256; ++k){ float kv = kr[k]; dot += qns[k]*kv; ss += kv*kv; }
            svs[t] = dot / fmaxf(sqrtf(ss), 1e-12f);
        }
        __syncthreads();
        if (t < 32){
            float temp = fmaxf(fabsf(temp_p[0]), 0.01f);
            float inv = 1.f / temp;
            float mx = -1e30f;
            for (int i = 0; i < 32; ++i) mx = fmaxf(mx, svs[i]);
            float se = 0.f;
            for (int i = 0; i < 32; ++i) se += expf((svs[i] - mx) * inv);
            att_out[idx*32 + t] = expf((svs[t] - mx) * inv) / se;
        }
        return;
    }

    // ---------------- enc/HGS path ----------------
    const int eb = blockIdx.x - 32;          // 0..511, 512 rows per block

    for (int e = t; e < 16*64*4; e += 256){
        int wd  = e & 3;
        int lam = (e >> 2) & 63;
        int f   = e >> 8;
        int ks  = f >> 2, jt = f & 3;
        int k0  = ks*16 + (lam >> 5)*8 + wd*2;
        int j   = jt*32 + (lam & 31);
        s_w1p[e] = pk_bf16(vw1[k0*128 + j], vw1[(k0+1)*128 + j]);
    }
    for (int e = t; e < NREG*128; e += 256) s_hgs[e] = 0.f;
    if (t < NREG) s_cnt[t] = 0.f;
    __syncthreads();

    float b1v[4], gv[4], btv[4];
    #pragma unroll
    for (int jt = 0; jt < 4; ++jt){
        b1v[jt] = vb1 [jt*32 + l31];
        gv [jt] = vg1 [jt*32 + l31];
        btv[jt] = vbt1[jt*32 + l31];
    }

    f32x16 hgs[4];
    #pragma unroll
    for (int nt = 0; nt < 4; ++nt)
        #pragma unroll
        for (int e = 0; e < 16; ++e) hgs[nt][e] = 0.f;
    int cnt_i = 0;

    const long rowbase = (long)eb*512 + (long)wid*128;

    // prologue: load + pack group 0 (16 u32 instead of 32 f32 live)
    unsigned pv[16]; int wiv_cur;
    {
        const float* rp = wval + (size_t)(rowbase + l31)*64 + lh*8;
        #pragma unroll
        for (int ks = 0; ks < 4; ++ks){
            float4 ra = *(const float4*)(rp + ks*16);
            float4 rb = *(const float4*)(rp + ks*16 + 4);
            pv[4*ks+0] = pk_bf16(ra.x, ra.y);
            pv[4*ks+1] = pk_bf16(ra.z, ra.w);
            pv[4*ks+2] = pk_bf16(rb.x, rb.y);
            pv[4*ks+3] = pk_bf16(rb.z, rb.w);
        }
        wiv_cur = widx[rowbase + l31];
    }

    #pragma unroll 1
    for (int g = 0; g < 4; ++g){
        const int cur_wiv = wiv_cur;
        const unsigned zm = (cur_wiv == 31) ? 0u : 0xFFFFFFFFu;

        // issue next-group loads early (raw floats live through LN/HGS only)
        float4 rf[8]; int wiv_nxt = 0;
        if (g < 3){
            const float* rp = wval + (size_t)(rowbase + (g+1)*32 + l31)*64 + lh*8;
            #pragma unroll
            for (int ks = 0; ks < 4; ++ks){
                rf[2*ks  ] = *(const float4*)(rp + ks*16);
                rf[2*ks+1] = *(const float4*)(rp + ks*16 + 4);
            }
            wiv_nxt = widx[rowbase + (g+1)*32 + l31];
        }

        // mask packed A fragments (1 AND per word)
        FR va[4];
        #pragma unroll
        for (int ks = 0; ks < 4; ++ks)
            #pragma unroll
            for (int w = 0; w < 4; ++w)
                va[ks].w[w] = (int)(pv[4*ks+w] & zm);

        // mm1: D1[b][j] = val @ w1  (+ b1 via accumulator init)
        f32x16 C1[4];
        #pragma unroll
        for (int jt = 0; jt < 4; ++jt)
            #pragma unroll
            for (int e = 0; e < 16; ++e) C1[jt][e] = b1v[jt];
        #pragma unroll
        for (int ks = 0; ks < 4; ++ks){
            FR bw[4];
            #pragma unroll
            for (int jt = 0; jt < 4; ++jt)
                bw[jt].w = *(const i32x4*)&s_w1p[((ks*4 + jt)*64 + lane)*4];
            #pragma unroll
            for (int jt = 0; jt < 4; ++jt)
                C1[jt] = __builtin_amdgcn_mfma_f32_32x32x16_bf16(va[ks].h, bw[jt].h, C1[jt], 0, 0, 0);
        }

        // LayerNorm over j (lanes): chunked e (4 at a time) to cap reg pressure
        #pragma unroll
        for (int ec = 0; ec < 4; ++ec){
            float s4[4], q4[4];
            #pragma unroll
            for (int u = 0; u < 4; ++u){
                int e = ec*4 + u;
                float x0 = C1[0][e], x1 = C1[1][e], x2 = C1[2][e], x3 = C1[3][e];
                s4[u] = (x0 + x1) + (x2 + x3);
                q4[u] = fmaf(x0,x0, fmaf(x1,x1, fmaf(x2,x2, x3*x3)));
            }
            #pragma unroll
            for (int o = 1; o <= 16; o <<= 1){
                #pragma unroll
                for (int u = 0; u < 4; ++u){
                    s4[u] += __shfl_xor(s4[u], o, 64);
                    q4[u] += __shfl_xor(q4[u], o, 64);
                }
            }
            #pragma unroll
            for (int u = 0; u < 4; ++u){
                int e = ec*4 + u;
                float m  = s4[u] * (1.f/128.f);
                float rs = rsqrtf(q4[u] * (1.f/128.f) - m*m + 1e-5f);
                #pragma unroll
                for (int jt = 0; jt < 4; ++jt)
                    C1[jt][e] = gelu_fast(fmaf((C1[jt][e] - m) * rs, gv[jt], btv[jt]));
            }
        }

        // one-hot fragments + integer counts (replaces cnt MFMA)
        FR oh[2];
        #pragma unroll
        for (int ks2 = 0; ks2 < 2; ++ks2){
            #pragma unroll
            for (int w = 0; w < 4; ++w){
                int b0 = ks2*16 + lh*8 + 2*w;
                int wa = __shfl(cur_wiv, b0,     64);
                int wb = __shfl(cur_wiv, b0 + 1, 64);
                unsigned x = (wa == l31 ? 0x3F80u : 0u) | (wb == l31 ? 0x3F800000u : 0u);
                oh[ks2].w[w] = (int)x;
                cnt_i += (int)((x >> 7) & 1u) + (int)((x >> 23) & 1u);
            }
        }

        // HGS[wi][j] += onehot^T @ hg  (nt outer so C1[nt] dies progressively)
        #pragma unroll
        for (int nt = 0; nt < 4; ++nt){
            #pragma unroll
            for (int ks2 = 0; ks2 < 2; ++ks2){
                const int rb = ks2*8;
                int P0 = (int)pk_bf16(C1[nt][rb+0], C1[nt][rb+1]);
                int P1 = (int)pk_bf16(C1[nt][rb+2], C1[nt][rb+3]);
                int Q0 = (int)pk_bf16(C1[nt][rb+4], C1[nt][rb+5]);
                int Q1 = (int)pk_bf16(C1[nt][rb+6], C1[nt][rb+7]);
                int sp0 = __shfl_xor(P0, 32, 64);
                int sq0 = __shfl_xor(Q0, 32, 64);
                int sp1 = __shfl_xor(P1, 32, 64);
                int sq1 = __shfl_xor(Q1, 32, 64);
                FR bf;
                bf.w[0] = lh ? sq0 : P0;
                bf.w[1] = lh ? sq1 : P1;
                bf.w[2] = lh ? Q0  : sp0;
                bf.w[3] = lh ? Q1  : sp1;
                hgs[nt] = __builtin_amdgcn_mfma_f32_32x32x16_bf16(oh[ks2].h, bf.h, hgs[nt], 0, 0, 0);
            }
        }

        // pack next group for use as A fragments
        if (g < 3){
            #pragma unroll
            for (int ks = 0; ks < 4; ++ks){
                pv[4*ks+0] = pk_bf16(rf[2*ks].x,   rf[2*ks].y);
                pv[4*ks+1] = pk_bf16(rf[2*ks].z,   rf[2*ks].w);
                pv[4*ks+2] = pk_bf16(rf[2*ks+1].x, rf[2*ks+1].y);
                pv[4*ks+3] = pk_bf16(rf[2*ks+1].z, rf[2*ks+1].w);
            }
            wiv_cur = wiv_nxt;
        }
    }

    // block-level reduce: LDS atomics (bank-clean: addr % 32 == l31)
    #pragma unroll
    for (int nt = 0; nt < 4; ++nt)
        #pragma unroll
        for (int e = 0; e < 16; ++e){
            int m = (e & 3) + 8*(e >> 2) + 4*lh;
            atomicAdd(&s_hgs[m*128 + nt*32 + l31], hgs[nt][e]);
        }
    atomicAdd(&s_cnt[l31], (float)cnt_i);
    __syncthreads();

    float* dst = hgs_g + (size_t)(eb & (NSLICE-1)) * SLICE_STRIDE;
    for (int e = t; e < NREG*128; e += 256) atomicAdd(&dst[e], s_hgs[e]);
    if (t < NREG) atomicAdd(&dst[NREG*128 + t], s_cnt[t]);
}

// ---------------------------------------------------------------------------
// Combine: slice-reduce, encsum = HGS@w2 + cnt*b2 (w2 LDS-staged), new_regs,
// rv_table. smemA aliases: phase1-2 = vw2 (8192f); phase3+ = enc(2048)+nr(2048).
// ---------------------------------------------------------------------------
__global__ void __launch_bounds__(256) k_combine(
    const float* __restrict__ att, const float* __restrict__ hgs_g,
    const float* __restrict__ regv, const float* __restrict__ vw2,
    const float* __restrict__ vb2, const float* __restrict__ wstr_p,
    float* __restrict__ rv_table, float* __restrict__ out_regs)
{
    __shared__ float smemA[8192];
    __shared__ float s_hgs[NREG*128];
    __shared__ float s_att[NREG*NREG];
    __shared__ float s_cnt[NREG];
    __shared__ float s_am[NREG];
    const int t = threadIdx.x;

    for (int e = t; e < 128*64; e += 256) smemA[e] = vw2[e];
    for (int e = t; e < NREG*128; e += 256){
        float s = 0.f;
        for (int sl = 0; sl < NSLICE; ++sl) s += hgs_g[sl*SLICE_STRIDE + e];
        s_hgs[e] = s;
    }
    if (t < NREG){
        float s = 0.f;
        for (int sl = 0; sl < NSLICE; ++sl) s += hgs_g[sl*SLICE_STRIDE + NREG*128 + t];
        s_cnt[t] = s;
    }
    for (int e = t; e < NREG*NREG; e += 256) s_att[e] = att[e];
    __syncthreads();

    // encsum into registers (reads s_hgs + smemA=w2)
    const int d  = t & 63;
    const int i0 = t >> 6;
    float enc_r[8];
    #pragma unroll
    for (int m = 0; m < 8; ++m){
        int i = i0 + 4*m;
        float acc = s_cnt[i] * vb2[d];
        for (int j = 0; j < 128; ++j)
            acc = fmaf(s_hgs[i*128 + j], smemA[j*64 + d], acc);
        enc_r[m] = acc;
    }
    if (t < NREG){
        float s = 0.f;
        for (int i = 0; i < NREG; ++i) s += s_cnt[i] * s_att[i*NREG + t];
        s_am[t] = s * (1.f / (float)B_TOTAL);
    }
    __syncthreads();   // all smemA(w2) reads done

    float* s_enc = smemA;          // [NREG*64]
    float* s_nr  = smemA + 2048;   // [NREG*64]
    #pragma unroll
    for (int m = 0; m < 8; ++m) s_enc[(i0 + 4*m)*64 + d] = enc_r[m];
    __syncthreads();

    const float s = 1.f / (1.f + expf(-wstr_p[0]));
    for (int e = t; e < NREG*BITW; e += 256){
        int r = e >> 6, dd = e & 63;
        float acc = 0.f;
        for (int i = 0; i < NREG; ++i) acc = fmaf(s_att[i*NREG + r], s_enc[i*64 + dd], acc);
        float nr = (1.f - s*s_am[r]) * regv[e] + (s / (float)B_TOTAL) * acc;
        s_nr[e] = nr;
        out_regs[e] = nr;
    }
    __syncthreads();
    for (int e = t; e < NREG*BITW; e += 256){
        int i = e >> 6, dd = e & 63;
        float acc = 0.f;
        for (int r = 0; r < NREG; ++r) acc = fmaf(s_att[i*NREG + r], s_nr[r*64 + dd], acc);
        rv_table[e] = (i == 31) ? 0.f : acc;
    }
}

// ---------------------------------------------------------------------------
// Read: read_value[b] = rv_table[read_idx[b]]  (float4 stores)
// ---------------------------------------------------------------------------
__global__ void __launch_bounds__(256) k_read(
    const int* __restrict__ ridx, const float* __restrict__ rv_table,
    float* __restrict__ out)
{
    __shared__ float s_rv[NREG*BITW];
    const int t = threadIdx.x;
    for (int e = t; e < NREG*BITW; e += 256) s_rv[e] = rv_table[e];
    __syncthreads();
    const int nq = B_TOTAL * 16;
    for (int q = blockIdx.x * 256 + t; q < nq; q += gridDim.x * 256){
        int row = q >> 4;
        int sub = (q & 15) << 2;
        int ri = ridx[row];
        *(float4*)(out + (size_t)q * 4) = *(const float4*)(&s_rv[ri*64 + sub]);
    }
}

extern "C" void kernel_launch(void* const* d_in, const int* in_sizes, int n_in,
                              void* d_out, int out_size, void* d_ws, size_t ws_size,
                              hipStream_t stream)
{
    (void)in_sizes; (void)n_in; (void)out_size; (void)ws_size;
    const int*   widx = (const int*)  d_in[0];
    const float* wval = (const float*)d_in[1];
    const int*   ridx = (const int*)  d_in[2];
    const float* regv = (const float*)d_in[3];
    const float* keys = (const float*)d_in[4];
    const float* qw1  = (const float*)d_in[5];
    const float* qb1  = (const float*)d_in[6];
    const float* qg1  = (const float*)d_in[7];
    const float* qbt1 = (const float*)d_in[8];
    const float* qw2  = (const float*)d_in[9];
    const float* qb2  = (const float*)d_in[10];
    const float* qg2  = (const float*)d_in[11];
    const float* qbt2 = (const float*)d_in[12];
    const float* qw3  = (const float*)d_in[13];
    const float* qb3  = (const float*)d_in[14];
    const float* vw1  = (const float*)d_in[15];
    const float* vb1  = (const float*)d_in[16];
    const float* vg1  = (const float*)d_in[17];
    const float* vbt1 = (const float*)d_in[18];
    const float* vw2  = (const float*)d_in[19];
    const float* vb2  = (const float*)d_in[20];
    const float* temp = (const float*)d_in[21];
    const float* wstr = (const float*)d_in[22];

    float* ws    = (float*)d_ws;
    float* att   = ws;                               // 1024
    float* hgs_g = ws + 1024;                        // 16 * 4128
    float* rvt   = ws + 1024 + NSLICE*SLICE_STRIDE;  // 2048
    float* out   = (float*)d_out;

    hipMemsetAsync(hgs_g, 0, (size_t)NSLICE*SLICE_STRIDE*sizeof(float), stream);
    k_fused  <<<544, 256, 0, stream>>>(wval, widx, vw1, vb1, vg1, vbt1,
                                       qw1,qb1,qg1,qbt1,qw2,qb2,qg2,qbt2,qw3,qb3,
                                       keys, temp, att, hgs_g);
    k_combine<<<1, 256, 0, stream>>>(att, hgs_g, regv, vw2, vb2, wstr,
                                     rvt, out + (size_t)B_TOTAL*64);
    k_read   <<<2048, 256, 0, stream>>>(ridx, rvt, out);
}

// Round 6
// 476.228 us; speedup vs baseline: 1.2584x; 1.2584x over previous
//
#include <hip/hip_runtime.h>
#include <hip/hip_bf16.h>
#include <math.h>

#define B_TOTAL 262144
#define NREG 32
#define BITW 64
#define NSLICE 16
#define SLICE_STRIDE (NREG*128 + NREG)   // 4128 floats per slice (HGS + cnt)

typedef float  f32x16 __attribute__((ext_vector_type(16)));
typedef short  short8 __attribute__((ext_vector_type(8)));
typedef int    i32x4  __attribute__((ext_vector_type(4)));

union FR { i32x4 w; short8 h; };

// v_cvt_pk_bf16_f32: dst.lo16 = bf16(a), dst.hi16 = bf16(b)  (RNE)
__device__ __forceinline__ unsigned pk_bf16(float a, float b){
    unsigned r;
    asm("v_cvt_pk_bf16_f32 %0, %1, %2" : "=v"(r) : "v"(a), "v"(b));
    return r;
}

// exact-erf gelu (used on the tiny att path only)
__device__ __forceinline__ float geluf(float x){
    return 0.5f * x * (1.0f + erff(x * 0.70710678118654752440f));
}

// tanh-form gelu: |err| < ~1.5e-3 abs, damped to ~1e-5 in outputs
__device__ __forceinline__ float gelu_fast(float x){
    float x2 = x*x;
    float t1 = fmaf(x2, 0.044715f, 1.0f);
    float z2 = x * t1 * 1.5957691216057308f;     // 2*sqrt(2/pi)
    float e  = __expf(z2);
    float r  = __builtin_amdgcn_rcpf(e + 1.0f);
    return x - x*r;                               // 0.5x(1+tanh z)
}

// ---------------------------------------------------------------------------
// Fused kernel: blocks 0..31 = attention table; blocks 32..543 = enc/HGS MFMA.
// Register budget is the binding constraint (launch_bounds(256,2) => 256
// unified regs/wave): no cross-group prefetch, HGS flushed per-nt per-group.
// ---------------------------------------------------------------------------
__global__ void __launch_bounds__(256, 2) k_fused(
    const float* __restrict__ wval, const int* __restrict__ widx,
    const float* __restrict__ vw1, const float* __restrict__ vb1,
    const float* __restrict__ vg1, const float* __restrict__ vbt1,
    const float* __restrict__ qw1, const float* __restrict__ qb1,
    const float* __restrict__ qg1, const float* __restrict__ qbt1,
    const float* __restrict__ qw2, const float* __restrict__ qb2,
    const float* __restrict__ qg2, const float* __restrict__ qbt2,
    const float* __restrict__ qw3, const float* __restrict__ qb3,
    const float* __restrict__ keys, const float* __restrict__ temp_p,
    float* __restrict__ att_out, float* __restrict__ hgs_g)
{
    __shared__ __align__(16) unsigned s_w1p[16*64*4];  // 16 frags x 64 lanes x 4 words
    __shared__ float s_hgs[NREG*128];
    __shared__ float s_cnt[NREG];
    __shared__ float red8[4];
    __shared__ float h1s[128];
    __shared__ float h2s[256];
    __shared__ float qns[256];
    __shared__ float svs[32];

    const int t    = threadIdx.x;
    const int lane = t & 63;
    const int wid  = t >> 6;
    const int l31  = lane & 31;
    const int lh   = lane >> 5;

    if (blockIdx.x < 32){
        // ---------------- attention table path (unchanged, verified) -------
        const int idx = blockIdx.x;
        auto blksum = [&](float v)->float{
            #pragma unroll
            for (int o = 32; o >= 1; o >>= 1) v += __shfl_xor(v, o, 64);
            if (lane == 0) red8[wid] = v;
            __syncthreads();
            float r = red8[0] + red8[1] + red8[2] + red8[3];
            __syncthreads();
            return r;
        };

        float a1 = 0.f;
        if (t < 128){
            a1 = qb1[t];
            #pragma unroll
            for (int k = 0; k < 5; ++k)
                a1 += (float)((idx >> k) & 1) * qw1[k*128 + t];
        }
        float m1 = blksum(t < 128 ? a1 : 0.f) * (1.f/128.f);
        float d1 = (t < 128) ? (a1 - m1) : 0.f;
        float v1 = blksum(d1*d1) * (1.f/128.f);
        if (t < 128) h1s[t] = geluf(d1 * rsqrtf(v1 + 1e-5f) * qg1[t] + qbt1[t]);
        __syncthreads();

        float a2 = qb2[t];
        for (int k = 0; k < 128; ++k) a2 += h1s[k] * qw2[k*256 + t];
        float m2 = blksum(a2) * (1.f/256.f);
        float d2 = a2 - m2;
        float v2 = blksum(d2*d2) * (1.f/256.f);
        h2s[t] = geluf(d2 * rsqrtf(v2 + 1e-5f) * qg2[t] + qbt2[t]);
        __syncthreads();

        float a3 = qb3[t];
        for (int k = 0; k < 256; ++k) a3 += h2s[k] * qw3[k*256 + t];
        float nrm = blksum(a3*a3);
        qns[t] = a3 / fmaxf(sqrtf(nrm), 1e-12f);
        __syncthreads();

        if (t < 32){
            const float* kr = keys + t * 256;
            float dot = 0.f, ss = 0.f;
            for (int k = 0; k < 256; ++k){ float kv = kr[k]; dot += qns[k]*kv; ss += kv*kv; }
            svs[t] = dot / fmaxf(sqrtf(ss), 1e-12f);
        }
        __syncthreads();
        if (t < 32){
            float temp = fmaxf(fabsf(temp_p[0]), 0.01f);
            float inv = 1.f / temp;
            float mx = -1e30f;
            for (int i = 0; i < 32; ++i) mx = fmaxf(mx, svs[i]);
            float se = 0.f;
            for (int i = 0; i < 32; ++i) se += expf((svs[i] - mx) * inv);
            att_out[idx*32 + t] = expf((svs[t] - mx) * inv) / se;
        }
        return;
    }

    // ---------------- enc/HGS path ----------------
    const int eb = blockIdx.x - 32;          // 0..511, 512 rows per block

    for (int e = t; e < 16*64*4; e += 256){
        int wd  = e & 3;
        int lam = (e >> 2) & 63;
        int f   = e >> 8;
        int ks  = f >> 2, jt = f & 3;
        int k0  = ks*16 + (lam >> 5)*8 + wd*2;
        int j   = jt*32 + (lam & 31);
        s_w1p[e] = pk_bf16(vw1[k0*128 + j], vw1[(k0+1)*128 + j]);
    }
    for (int e = t; e < NREG*128; e += 256) s_hgs[e] = 0.f;
    if (t < NREG) s_cnt[t] = 0.f;
    __syncthreads();

    float b1v[4], gv[4], btv[4];
    #pragma unroll
    for (int jt = 0; jt < 4; ++jt){
        b1v[jt] = vb1 [jt*32 + l31];
        gv [jt] = vg1 [jt*32 + l31];
        btv[jt] = vbt1[jt*32 + l31];
    }
    int cnt_i = 0;

    const long rowbase = (long)eb*512 + (long)wid*128;

    #pragma unroll 1
    for (int g = 0; g < 4; ++g){
        // ---- load this group's 8 rows-worth (per lane) + widx; no prefetch
        const float* rp = wval + (size_t)(rowbase + g*32 + l31)*64 + lh*8;
        float4 r0 = *(const float4*)(rp +  0);
        float4 r1 = *(const float4*)(rp +  4);
        float4 r2 = *(const float4*)(rp + 16);
        float4 r3 = *(const float4*)(rp + 20);
        float4 r4 = *(const float4*)(rp + 32);
        float4 r5 = *(const float4*)(rp + 36);
        float4 r6 = *(const float4*)(rp + 48);
        float4 r7 = *(const float4*)(rp + 52);
        const int cur_wiv = widx[rowbase + g*32 + l31];
        const unsigned zm = (cur_wiv == 31) ? 0u : 0xFFFFFFFFu;

        FR va[4];
        va[0].w[0] = (int)(pk_bf16(r0.x, r0.y) & zm);
        va[0].w[1] = (int)(pk_bf16(r0.z, r0.w) & zm);
        va[0].w[2] = (int)(pk_bf16(r1.x, r1.y) & zm);
        va[0].w[3] = (int)(pk_bf16(r1.z, r1.w) & zm);
        va[1].w[0] = (int)(pk_bf16(r2.x, r2.y) & zm);
        va[1].w[1] = (int)(pk_bf16(r2.z, r2.w) & zm);
        va[1].w[2] = (int)(pk_bf16(r3.x, r3.y) & zm);
        va[1].w[3] = (int)(pk_bf16(r3.z, r3.w) & zm);
        va[2].w[0] = (int)(pk_bf16(r4.x, r4.y) & zm);
        va[2].w[1] = (int)(pk_bf16(r4.z, r4.w) & zm);
        va[2].w[2] = (int)(pk_bf16(r5.x, r5.y) & zm);
        va[2].w[3] = (int)(pk_bf16(r5.z, r5.w) & zm);
        va[3].w[0] = (int)(pk_bf16(r6.x, r6.y) & zm);
        va[3].w[1] = (int)(pk_bf16(r6.z, r6.w) & zm);
        va[3].w[2] = (int)(pk_bf16(r7.x, r7.y) & zm);
        va[3].w[3] = (int)(pk_bf16(r7.z, r7.w) & zm);

        // mm1: D1[b][j] = val @ w1  (+ b1 via accumulator init)
        f32x16 C1[4];
        #pragma unroll
        for (int jt = 0; jt < 4; ++jt)
            #pragma unroll
            for (int e = 0; e < 16; ++e) C1[jt][e] = b1v[jt];
        #pragma unroll
        for (int ks = 0; ks < 4; ++ks){
            FR bw[4];
            #pragma unroll
            for (int jt = 0; jt < 4; ++jt)
                bw[jt].w = *(const i32x4*)&s_w1p[((ks*4 + jt)*64 + lane)*4];
            #pragma unroll
            for (int jt = 0; jt < 4; ++jt)
                C1[jt] = __builtin_amdgcn_mfma_f32_32x32x16_bf16(va[ks].h, bw[jt].h, C1[jt], 0, 0, 0);
        }

        // LayerNorm over j (lanes): chunked e (4 at a time) to cap reg pressure
        #pragma unroll
        for (int ec = 0; ec < 4; ++ec){
            float s4[4], q4[4];
            #pragma unroll
            for (int u = 0; u < 4; ++u){
                int e = ec*4 + u;
                float x0 = C1[0][e], x1 = C1[1][e], x2 = C1[2][e], x3 = C1[3][e];
                s4[u] = (x0 + x1) + (x2 + x3);
                q4[u] = fmaf(x0,x0, fmaf(x1,x1, fmaf(x2,x2, x3*x3)));
            }
            #pragma unroll
            for (int o = 1; o <= 16; o <<= 1){
                #pragma unroll
                for (int u = 0; u < 4; ++u){
                    s4[u] += __shfl_xor(s4[u], o, 64);
                    q4[u] += __shfl_xor(q4[u], o, 64);
                }
            }
            #pragma unroll
            for (int u = 0; u < 4; ++u){
                int e = ec*4 + u;
                float m  = s4[u] * (1.f/128.f);
                float rs = rsqrtf(q4[u] * (1.f/128.f) - m*m + 1e-5f);
                #pragma unroll
                for (int jt = 0; jt < 4; ++jt)
                    C1[jt][e] = gelu_fast(fmaf((C1[jt][e] - m) * rs, gv[jt], btv[jt]));
            }
        }

        // one-hot fragments + integer counts
        FR oh[2];
        #pragma unroll
        for (int ks2 = 0; ks2 < 2; ++ks2){
            #pragma unroll
            for (int w = 0; w < 4; ++w){
                int b0 = ks2*16 + lh*8 + 2*w;
                int wa = __shfl(cur_wiv, b0,     64);
                int wb = __shfl(cur_wiv, b0 + 1, 64);
                unsigned x = (wa == l31 ? 0x3F80u : 0u) | (wb == l31 ? 0x3F800000u : 0u);
                oh[ks2].w[w] = (int)x;
                cnt_i += (int)((x >> 7) & 1u) + (int)((x >> 23) & 1u);
            }
        }

        // HGS[wi][j] += onehot^T @ hg ; transient 16-reg accumulator per nt,
        // flushed to LDS immediately (keeps unified reg peak ~C1+16).
        #pragma unroll
        for (int nt = 0; nt < 4; ++nt){
            f32x16 hgsl;
            #pragma unroll
            for (int e = 0; e < 16; ++e) hgsl[e] = 0.f;
            #pragma unroll
            for (int ks2 = 0; ks2 < 2; ++ks2){
                const int rb = ks2*8;
                int P0 = (int)pk_bf16(C1[nt][rb+0], C1[nt][rb+1]);
                int P1 = (int)pk_bf16(C1[nt][rb+2], C1[nt][rb+3]);
                int Q0 = (int)pk_bf16(C1[nt][rb+4], C1[nt][rb+5]);
                int Q1 = (int)pk_bf16(C1[nt][rb+6], C1[nt][rb+7]);
                int sp0 = __shfl_xor(P0, 32, 64);
                int sq0 = __shfl_xor(Q0, 32, 64);
                int sp1 = __shfl_xor(P1, 32, 64);
                int sq1 = __shfl_xor(Q1, 32, 64);
                FR bf;
                bf.w[0] = lh ? sq0 : P0;
                bf.w[1] = lh ? sq1 : P1;
                bf.w[2] = lh ? Q0  : sp0;
                bf.w[3] = lh ? Q1  : sp1;
                hgsl = __builtin_amdgcn_mfma_f32_32x32x16_bf16(oh[ks2].h, bf.h, hgsl, 0, 0, 0);
            }
            #pragma unroll
            for (int e = 0; e < 16; ++e){
                int m = (e & 3) + 8*(e >> 2) + 4*lh;
                atomicAdd(&s_hgs[m*128 + nt*32 + l31], hgsl[e]);
            }
        }
    }

    atomicAdd(&s_cnt[l31], (float)cnt_i);
    __syncthreads();

    float* dst = hgs_g + (size_t)(eb & (NSLICE-1)) * SLICE_STRIDE;
    for (int e = t; e < NREG*128; e += 256) atomicAdd(&dst[e], s_hgs[e]);
    if (t < NREG) atomicAdd(&dst[NREG*128 + t], s_cnt[t]);
}

// ---------------------------------------------------------------------------
// Combine: slice-reduce, encsum = HGS@w2 + cnt*b2 (w2 LDS-staged), new_regs,
// rv_table. smemA aliases: phase1-2 = vw2 (8192f); phase3+ = enc(2048)+nr(2048).
// ---------------------------------------------------------------------------
__global__ void __launch_bounds__(256) k_combine(
    const float* __restrict__ att, const float* __restrict__ hgs_g,
    const float* __restrict__ regv, const float* __restrict__ vw2,
    const float* __restrict__ vb2, const float* __restrict__ wstr_p,
    float* __restrict__ rv_table, float* __restrict__ out_regs)
{
    __shared__ float smemA[8192];
    __shared__ float s_hgs[NREG*128];
    __shared__ float s_att[NREG*NREG];
    __shared__ float s_cnt[NREG];
    __shared__ float s_am[NREG];
    const int t = threadIdx.x;

    for (int e = t; e < 128*64; e += 256) smemA[e] = vw2[e];
    for (int e = t; e < NREG*128; e += 256){
        float s = 0.f;
        for (int sl = 0; sl < NSLICE; ++sl) s += hgs_g[sl*SLICE_STRIDE + e];
        s_hgs[e] = s;
    }
    if (t < NREG){
        float s = 0.f;
        for (int sl = 0; sl < NSLICE; ++sl) s += hgs_g[sl*SLICE_STRIDE + NREG*128 + t];
        s_cnt[t] = s;
    }
    for (int e = t; e < NREG*NREG; e += 256) s_att[e] = att[e];
    __syncthreads();

    // encsum into registers (reads s_hgs + smemA=w2)
    const int d  = t & 63;
    const int i0 = t >> 6;
    float enc_r[8];
    #pragma unroll
    for (int m = 0; m < 8; ++m){
        int i = i0 + 4*m;
        float acc = s_cnt[i] * vb2[d];
        for (int j = 0; j < 128; ++j)
            acc = fmaf(s_hgs[i*128 + j], smemA[j*64 + d], acc);
        enc_r[m] = acc;
    }
    if (t < NREG){
        float s = 0.f;
        for (int i = 0; i < NREG; ++i) s += s_cnt[i] * s_att[i*NREG + t];
        s_am[t] = s * (1.f / (float)B_TOTAL);
    }
    __syncthreads();   // all smemA(w2) reads done

    float* s_enc = smemA;          // [NREG*64]
    float* s_nr  = smemA + 2048;   // [NREG*64]
    #pragma unroll
    for (int m = 0; m < 8; ++m) s_enc[(i0 + 4*m)*64 + d] = enc_r[m];
    __syncthreads();

    const float s = 1.f / (1.f + expf(-wstr_p[0]));
    for (int e = t; e < NREG*BITW; e += 256){
        int r = e >> 6, dd = e & 63;
        float acc = 0.f;
        for (int i = 0; i < NREG; ++i) acc = fmaf(s_att[i*NREG + r], s_enc[i*64 + dd], acc);
        float nr = (1.f - s*s_am[r]) * regv[e] + (s / (float)B_TOTAL) * acc;
        s_nr[e] = nr;
        out_regs[e] = nr;
    }
    __syncthreads();
    for (int e = t; e < NREG*BITW; e += 256){
        int i = e >> 6, dd = e & 63;
        float acc = 0.f;
        for (int r = 0; r < NREG; ++r) acc = fmaf(s_att[i*NREG + r], s_nr[r*64 + dd], acc);
        rv_table[e] = (i == 31) ? 0.f : acc;
    }
}

// ---------------------------------------------------------------------------
// Read: read_value[b] = rv_table[read_idx[b]]  (float4 stores)
// ---------------------------------------------------------------------------
__global__ void __launch_bounds__(256) k_read(
    const int* __restrict__ ridx, const float* __restrict__ rv_table,
    float* __restrict__ out)
{
    __shared__ float s_rv[NREG*BITW];
    const int t = threadIdx.x;
    for (int e = t; e < NREG*BITW; e += 256) s_rv[e] = rv_table[e];
    __syncthreads();
    const int nq = B_TOTAL * 16;
    for (int q = blockIdx.x * 256 + t; q < nq; q += gridDim.x * 256){
        int row = q >> 4;
        int sub = (q & 15) << 2;
        int ri = ridx[row];
        *(float4*)(out + (size_t)q * 4) = *(const float4*)(&s_rv[ri*64 + sub]);
    }
}

extern "C" void kernel_launch(void* const* d_in, const int* in_sizes, int n_in,
                              void* d_out, int out_size, void* d_ws, size_t ws_size,
                              hipStream_t stream)
{
    (void)in_sizes; (void)n_in; (void)out_size; (void)ws_size;
    const int*   widx = (const int*)  d_in[0];
    const float* wval = (const float*)d_in[1];
    const int*   ridx = (const int*)  d_in[2];
    const float* regv = (const float*)d_in[3];
    const float* keys = (const float*)d_in[4];
    const float* qw1  = (const float*)d_in[5];
    const float* qb1  = (const float*)d_in[6];
    const float* qg1  = (const float*)d_in[7];
    const float* qbt1 = (const float*)d_in[8];
    const float* qw2  = (const float*)d_in[9];
    const float* qb2  = (const float*)d_in[10];
    const float* qg2  = (const float*)d_in[11];
    const float* qbt2 = (const float*)d_in[12];
    const float* qw3  = (const float*)d_in[13];
    const float* qb3  = (const float*)d_in[14];
    const float* vw1  = (const float*)d_in[15];
    const float* vb1  = (const float*)d_in[16];
    const float* vg1  = (const float*)d_in[17];
    const float* vbt1 = (const float*)d_in[18];
    const float* vw2  = (const float*)d_in[19];
    const float* vb2  = (const float*)d_in[20];
    const float* temp = (const float*)d_in[21];
    const float* wstr = (const float*)d_in[22];

    float* ws    = (float*)d_ws;
    float* att   = ws;                               // 1024
    float* hgs_g = ws + 1024;                        // 16 * 4128
    float* rvt   = ws + 1024 + NSLICE*SLICE_STRIDE;  // 2048
    float* out   = (float*)d_out;

    hipMemsetAsync(hgs_g, 0, (size_t)NSLICE*SLICE_STRIDE*sizeof(float), stream);
    k_fused  <<<544, 256, 0, stream>>>(wval, widx, vw1, vb1, vg1, vbt1,
                                       qw1,qb1,qg1,qbt1,qw2,qb2,qg2,qbt2,qw3,qb3,
                                       keys, temp, att, hgs_g);
    k_combine<<<1, 256, 0, stream>>>(att, hgs_g, regv, vw2, vb2, wstr,
                                     rvt, out + (size_t)B_TOTAL*64);
    k_read   <<<2048, 256, 0, stream>>>(ridx, rvt, out);
}